// Round 2
// baseline (1318.777 us; speedup 1.0000x reference)
//
#include <hip/hip_runtime.h>

// RegressorHybrid: per-edge 2x MLP (128->64->64->32->1, lrelu 0.01), E=2M, H=64.
// Round 8: pin the VGPR tier. R7 (MLP-split blocks, LDS 40960 -> 4 blocks/CU)
// regressed 287->1100us because the backend treated launch_bounds(256,4) as a
// MINIMUM and squeezed to the 64-VGPR/8-waves tier, spilling ~40 loop regs:
// WRITE_SIZE 15.6->120MB (scratch), warm lines evicted by scratch thrash, and
// per the R1-R5 law each missing consume b128 lane-request = own 64B fill:
// 125K tiles x 256 reqs x 64B x 2 half-grids = 4.0GB = measured FETCH (4.07GB).
// LDS already caps at 4 blocks/CU, so the squeeze bought nothing.
// Fix: amdgpu_waves_per_eu(4,4) pins min=max=4 waves/EU -> hard 128-reg budget,
// no spill-to-64. Loop demand ~100-110 regs fits. Gnxt prefetch back at loop
// top (R6-proven). Rest identical to R7: each block runs ONE MLP
// (m = blockIdx >= grid/2), biases/w4 in LDS, block b and b+512 share an XCD
// (512%8==0) and tile schedule so duplicated warms dedup in L2.
// MFMA layouts: A[m=lane&15][k=(lane>>4)*8+j], B[k=(lane>>4)*8+j][n=lane&15],
//               C/D[row=4*(lane>>4)+reg][col=lane&15].

typedef _Float16 half8  __attribute__((ext_vector_type(8)));
typedef _Float16 half4v __attribute__((ext_vector_type(4)));
typedef float    float4v __attribute__((ext_vector_type(4)));

#define LDS_W       28672          // w1f 16384 + w2f 8192 + w3f 4096
#define LDS_REST    12288          // w4f 2048 + b1f 4096 + b2f 4096 + b3f 2048
#define LDS_TOTAL   40960          // exactly 4 blocks/CU (163840/40960)
#define W1F 0
#define W2F 16384
#define W3F 24576
#define RW4F 28672
#define RB1F 30720
#define RB2F 34816
#define RB3F 38912
#define WS_REST_OFF 57344
#define WS_X16_OFF  81920

__device__ __forceinline__ float lrelu(float x) { return fmaxf(x, 0.01f * x); }

__device__ __forceinline__ int uperm(int k) {
    return 16 * (2 * ((k >> 2) & 1) + ((k >> 5) & 1)) + 4 * ((k >> 3) & 3) + (k & 3);
}

// ---- pack one MLP's weights/biases into per-lane fragment order ----
__global__ void prep_frags(const float* __restrict__ w1, const float* __restrict__ b1,
                           const float* __restrict__ w2, const float* __restrict__ b2,
                           const float* __restrict__ w3, const float* __restrict__ b3,
                           const float* __restrict__ w4,
                           unsigned char* __restrict__ dstL,
                           unsigned char* __restrict__ dstR)
{
    int idx = blockIdx.x * blockDim.x + threadIdx.x;
    if (idx < 8192) {                      // w1f: [16 frags][64 lanes][8 f16]
        int L = (idx >> 3) & 63, j = idx & 7, f = idx >> 9;
        int q = L >> 4, mm = L & 15, t = f >> 2, s = f & 3;
        int k = 32 * s + 8 * q + j;
        ((_Float16*)(dstL + W1F))[idx] = (_Float16)w1[k * 64 + 16 * t + mm];
        return;
    }
    idx -= 8192;
    if (idx < 4096) {                      // w2f: [8][64][8]
        int L = (idx >> 3) & 63, j = idx & 7, f = idx >> 9;
        int q = L >> 4, mm = L & 15, t = f >> 1, s = f & 1;
        int u = uperm(32 * s + 8 * q + j);
        ((_Float16*)(dstL + W2F))[idx] = (_Float16)w2[u * 64 + 16 * t + mm];
        return;
    }
    idx -= 4096;
    if (idx < 2048) {                      // w3f: [4][64][8]
        int L = (idx >> 3) & 63, j = idx & 7, f = idx >> 9;
        int q = L >> 4, mm = L & 15, t = f >> 1, s = f & 1;
        int u = uperm(32 * s + 8 * q + j);
        ((_Float16*)(dstL + W3F))[idx] = (_Float16)w3[u * 32 + 16 * t + mm];
        return;
    }
    idx -= 2048;
    if (idx < 512) {                       // w4f
        int L = idx >> 3, j = idx & 7;
        int q = L >> 4, t = j >> 2, r = j & 3;
        ((float*)(dstR + 0))[idx] = w4[16 * t + 4 * q + r];
        return;
    }
    idx -= 512;
    if (idx < 1024) {                      // b1f
        int t = idx >> 8, L = (idx >> 2) & 63, r = idx & 3, q = L >> 4;
        ((float*)(dstR + 2048))[idx] = b1[16 * t + 4 * q + r];
        return;
    }
    idx -= 1024;
    if (idx < 1024) {                      // b2f
        int t = idx >> 8, L = (idx >> 2) & 63, r = idx & 3, q = L >> 4;
        ((float*)(dstR + 6144))[idx] = b2[16 * t + 4 * q + r];
        return;
    }
    idx -= 1024;
    if (idx < 512) {                       // b3f
        int t = idx >> 8, L = (idx >> 2) & 63, r = idx & 3, q = L >> 4;
        ((float*)(dstR + 10240))[idx] = b3[16 * t + 4 * q + r];
        return;
    }
}

// ---- convert node tables fp32 -> f16 ----
__global__ void prep_nodes(const float* __restrict__ xs, const float* __restrict__ xd,
                           _Float16* __restrict__ os, _Float16* __restrict__ od, int n4)
{
    int stride = gridDim.x * blockDim.x;
    for (int i = blockIdx.x * blockDim.x + threadIdx.x; i < n4; i += stride) {
        float4v a = ((const float4v*)xs)[i];
        float4v b = ((const float4v*)xd)[i];
        half4v ha, hb;
#pragma unroll
        for (int j = 0; j < 4; ++j) { ha[j] = (_Float16)a[j]; hb[j] = (_Float16)b[j]; }
        ((half4v*)os)[i] = ha;
        ((half4v*)od)[i] = hb;
    }
}

__device__ __forceinline__ half8 repack2(float4v lo, float4v hi) {
    half8 r;
#pragma unroll
    for (int j = 0; j < 4; ++j) r[j] = (_Float16)lrelu(lo[j]);
#pragma unroll
    for (int j = 0; j < 4; ++j) r[4 + j] = (_Float16)lrelu(hi[j]);
    return r;
}

// R2-style consume gather: lane (q,n) loads chunk q of edge n's 4 lines.
// These requests HIT L1/L2 (warmed 3 iterations earlier) -> no fills.
__device__ __forceinline__ void gather_tile(const _Float16* __restrict__ xs,
                                            const _Float16* __restrict__ xd,
                                            const int* __restrict__ eidx,
                                            int nE, int tile, int q, int n, int4* G)
{
    int e = tile * 16 + n;
    int ec = e < nE ? e : nE - 1;
    int si = eidx[ec];
    int di = eidx[nE + ec];
    const char* rs = (const char*)(xs + (size_t)si * 64);
    const char* rd = (const char*)(xd + (size_t)di * 64);
    G[0] = *(const int4*)(rs + 16 * q);
    G[1] = *(const int4*)(rs + 64 + 16 * q);
    G[2] = *(const int4*)(rd + 16 * q);
    G[3] = *(const int4*)(rd + 64 + 16 * q);
}

// warm pass: lane (c=q, n) touches line (edge n, combo c) once -> 64 distinct
// lines per instruction, exactly one 64B fill each.
__device__ __forceinline__ int4 warm_tile(const _Float16* __restrict__ xs,
                                          const _Float16* __restrict__ xd,
                                          const int* __restrict__ eidx,
                                          int nE, int tile, int c, int n)
{
    int e = tile * 16 + n;
    int ec = e < nE ? e : nE - 1;
    int idx = (c & 2) ? eidx[nE + ec] : eidx[ec];
    const char* base = (const char*)(((c & 2) ? xd : xs) + (size_t)idx * 64);
    return *(const int4*)(base + (c & 1) * 64);
}

__global__ __launch_bounds__(256) __attribute__((amdgpu_waves_per_eu(4, 4)))
void edge_mlp_mfma(const unsigned char* __restrict__ ws,
                   const _Float16* __restrict__ xs, const _Float16* __restrict__ xd,
                   const int* __restrict__ eidx,
                   const float* __restrict__ eb4p, const float* __restrict__ wb4p,
                   float* __restrict__ out, int nE, int ntiles)
{
    __shared__ unsigned char lds[LDS_TOTAL];
    const int halfgrid = gridDim.x >> 1;
    const int m = blockIdx.x >= halfgrid ? 1 : 0;   // 0: exists-MLP, 1: weight-MLP
    const int bid = blockIdx.x - m * halfgrid;
    {
        const uint4* s = (const uint4*)(ws + m * LDS_W);
        uint4* d = (uint4*)lds;
        for (int i = threadIdx.x; i < LDS_W / 16; i += 256) d[i] = s[i];
        const uint4* s2 = (const uint4*)(ws + WS_REST_OFF + m * LDS_REST);
        uint4* d2 = (uint4*)(lds + LDS_W);
        for (int i = threadIdx.x; i < LDS_REST / 16; i += 256) d2[i] = s2[i];
    }
    __syncthreads();

    const int lane = threadIdx.x & 63;
    const int q = lane >> 4, n = lane & 15;
    const int wv = __builtin_amdgcn_readfirstlane(threadIdx.x >> 6);
    const int wid = (bid << 2) | wv;
    const int nwaves = halfgrid << 2;
    const float b4s = m ? wb4p[0] : eb4p[0];
    float* __restrict__ outm = out + (m ? nE : 0);

    int4 Gcur[4], Gnxt[4];
    int4 W0 = {0,0,0,0}, W1 = {0,0,0,0}, W2 = {0,0,0,0}, junk = {0,0,0,0};

    int tile = wid;
    if (tile < ntiles) {
        int t1 = tile + nwaves;     if (t1 >= ntiles) t1 = ntiles - 1;
        int t2 = tile + 2 * nwaves; if (t2 >= ntiles) t2 = ntiles - 1;
        W0 = warm_tile(xs, xd, eidx, nE, tile, q, n);
        W1 = warm_tile(xs, xd, eidx, nE, t1, q, n);
        W2 = warm_tile(xs, xd, eidx, nE, t2, q, n);
        gather_tile(xs, xd, eidx, nE, tile, q, n, Gcur);
    }

#pragma unroll 1
    for (; tile < ntiles; tile += nwaves) {
        half8 B1[4];
#pragma unroll
        for (int s = 0; s < 4; ++s) B1[s] = __builtin_bit_cast(half8, Gcur[s]);

        // prefetch next tile's consume gather (hits warmed lines)
        int tn = tile + nwaves;
        if (tn < ntiles)
            gather_tile(xs, xd, eidx, nE, tn, q, n, Gnxt);

        // fold oldest warm (2 iters old -> complete), rotate, issue new warm
        junk.x ^= W0.x; junk.y ^= W0.y; junk.z ^= W0.z; junk.w ^= W0.w;
        W0 = W1; W1 = W2;
        {
            int tw = tile + 3 * nwaves;
            if (tw >= ntiles) tw = ntiles - 1;
            W2 = warm_tile(xs, xd, eidx, nE, tw, q, n);
        }

        // ---- layer 1: 128 -> 64 (bias via C-init from LDS) ----
        float4v acc[4];
#pragma unroll
        for (int t = 0; t < 4; ++t) {
            acc[t] = *(const float4v*)(lds + RB1F + (t * 64 + lane) * 16);
#pragma unroll
            for (int s = 0; s < 4; ++s) {
                half8 A = *(const half8*)(lds + W1F + ((t * 4 + s) * 64 + lane) * 16);
                acc[t] = __builtin_amdgcn_mfma_f32_16x16x32_f16(A, B1[s], acc[t], 0, 0, 0);
            }
        }

        // ---- layer 2: 64 -> 64 ----
        half8 B2[2] = { repack2(acc[0], acc[2]), repack2(acc[1], acc[3]) };
        float4v acc2[4];
#pragma unroll
        for (int t = 0; t < 4; ++t) {
            acc2[t] = *(const float4v*)(lds + RB2F + (t * 64 + lane) * 16);
#pragma unroll
            for (int s = 0; s < 2; ++s) {
                half8 A = *(const half8*)(lds + W2F + ((t * 2 + s) * 64 + lane) * 16);
                acc2[t] = __builtin_amdgcn_mfma_f32_16x16x32_f16(A, B2[s], acc2[t], 0, 0, 0);
            }
        }
        // ---- layer 3: 64 -> 32 ----
        half8 B3[2] = { repack2(acc2[0], acc2[2]), repack2(acc2[1], acc2[3]) };
        float4v acc3[2];
#pragma unroll
        for (int t = 0; t < 2; ++t) {
            acc3[t] = *(const float4v*)(lds + RB3F + (t * 64 + lane) * 16);
#pragma unroll
            for (int s = 0; s < 2; ++s) {
                half8 A = *(const half8*)(lds + W3F + ((t * 2 + s) * 64 + lane) * 16);
                acc3[t] = __builtin_amdgcn_mfma_f32_16x16x32_f16(A, B3[s], acc3[t], 0, 0, 0);
            }
        }
        // ---- layer 4: 32 -> 1 ----
        float4v w40 = *(const float4v*)(lds + RW4F + lane * 32);
        float4v w41 = *(const float4v*)(lds + RW4F + lane * 32 + 16);
        float o = 0.f;
#pragma unroll
        for (int r = 0; r < 4; ++r) o = fmaf(lrelu(acc3[0][r]), w40[r], o);
#pragma unroll
        for (int r = 0; r < 4; ++r) o = fmaf(lrelu(acc3[1][r]), w41[r], o);
        o += __shfl_xor(o, 16, 64);
        o += __shfl_xor(o, 32, 64);

        int e = tile * 16 + n;
        if (q == 0 && e < nE)
            outm[e] = o + b4s;

#pragma unroll
        for (int s = 0; s < 4; ++s) Gcur[s] = Gnxt[s];
    }

    // consume warm registers (never-taken, data-dependent guard defeats DCE)
    junk.x ^= W0.x ^ W1.x ^ W2.x;
    junk.y ^= W0.y ^ W1.y ^ W2.y;
    junk.z ^= W0.z ^ W1.z ^ W2.z;
    junk.w ^= W0.w ^ W1.w ^ W2.w;
    if (nE < 0 && (junk.x | junk.y | junk.z | junk.w) != 0)
        out[0] = -1.0f;
}

extern "C" void kernel_launch(void* const* d_in, const int* in_sizes, int n_in,
                              void* d_out, int out_size, void* d_ws, size_t ws_size,
                              hipStream_t stream)
{
    const float* x_src = (const float*)d_in[0];
    const float* x_dst = (const float*)d_in[1];
    const int*   eidx  = (const int*)d_in[2];
    const float* ew1 = (const float*)d_in[3];
    const float* eb1 = (const float*)d_in[4];
    const float* ww1 = (const float*)d_in[5];
    const float* wb1 = (const float*)d_in[6];
    const float* ew2 = (const float*)d_in[7];
    const float* eb2 = (const float*)d_in[8];
    const float* ww2 = (const float*)d_in[9];
    const float* wb2 = (const float*)d_in[10];
    const float* ew3 = (const float*)d_in[11];
    const float* eb3 = (const float*)d_in[12];
    const float* ww3 = (const float*)d_in[13];
    const float* wb3 = (const float*)d_in[14];
    const float* ew4 = (const float*)d_in[15];
    const float* eb4 = (const float*)d_in[16];
    const float* ww4 = (const float*)d_in[17];
    const float* wb4 = (const float*)d_in[18];
    float* out = (float*)d_out;

    const int nE = in_sizes[2] / 2;          // 2 x E index array (int32)
    const int nNodeElems = in_sizes[0];      // N_NODES * 64
    unsigned char* ws = (unsigned char*)d_ws;
    _Float16* xs16 = (_Float16*)(ws + WS_X16_OFF);
    _Float16* xd16 = xs16 + nNodeElems;

    prep_frags<<<68, 256, 0, stream>>>(ew1, eb1, ew2, eb2, ew3, eb3, ew4,
                                       ws, ws + WS_REST_OFF);
    prep_frags<<<68, 256, 0, stream>>>(ww1, wb1, ww2, wb2, ww3, wb3, ww4,
                                       ws + LDS_W, ws + WS_REST_OFF + LDS_REST);
    prep_nodes<<<1024, 256, 0, stream>>>(x_src, x_dst, xs16, xd16, nNodeElems / 4);

    const int ntiles = (nE + 15) / 16;
    edge_mlp_mfma<<<1024, 256, 0, stream>>>(ws, xs16, xd16, eidx, eb4, wb4,
                                            out, nE, ntiles);
}

// Round 3
// 388.144 us; speedup vs baseline: 3.3976x; 3.3976x over previous
//
#include <hip/hip_runtime.h>

// RegressorHybrid: per-edge 2x MLP (128->64->64->32->1, lrelu 0.01), E=2M, H=64.
// Round 9: split-MLP blocks WITHOUT an occupancy request. R7/R8 (min 4
// waves/EU) hit a spill-chase: budget 512/4=128 total (unified VGPR+AGPR,
// split ~64/64), demand ~140 -> allocator honored the request by spilling
// arch regs to 64 (WRITE 131MB scratch, warm lines evicted, FETCH 4.4GB by
// the R1-R5 fill law). R6's identical request was infeasible (demand 212) so
// the allocator IGNORED it -> 212 spill-free. Lesson: never request an
// occupancy tier within spill-chasing distance of demand.
// Fix: launch_bounds(256,2) -> budget 256, allocator allocates honestly
// (~150-190, no spill); occupancy falls out: <=170 -> 3 waves/SIMD (12/CU,
// 1.5x R6), <=128 -> 4 (16/CU). Structure kept from R7: each block runs ONE
// MLP (m = blockIdx >= grid/2), LDS = 28KB weights + 12KB bias/w4 = 40960B,
// biases C-init from LDS (no per-layer vmem waits), block b and b+512 share
// an XCD (512%8==0) and tile schedule so duplicated warms dedup in L2.
// Warm-pass law (R1-R5) retained: one warm b128 per tile covers its 64 lines
// (1 fill each), 3 iterations ahead; consume gathers hit L1/L2.
// MFMA layouts: A[m=lane&15][k=(lane>>4)*8+j], B[k=(lane>>4)*8+j][n=lane&15],
//               C/D[row=4*(lane>>4)+reg][col=lane&15].

typedef _Float16 half8  __attribute__((ext_vector_type(8)));
typedef _Float16 half4v __attribute__((ext_vector_type(4)));
typedef float    float4v __attribute__((ext_vector_type(4)));

#define LDS_W       28672          // w1f 16384 + w2f 8192 + w3f 4096
#define LDS_REST    12288          // w4f 2048 + b1f 4096 + b2f 4096 + b3f 2048
#define LDS_TOTAL   40960          // 4 blocks/CU by LDS (163840/40960)
#define W1F 0
#define W2F 16384
#define W3F 24576
#define RW4F 28672
#define RB1F 30720
#define RB2F 34816
#define RB3F 38912
#define WS_REST_OFF 57344
#define WS_X16_OFF  81920

__device__ __forceinline__ float lrelu(float x) { return fmaxf(x, 0.01f * x); }

__device__ __forceinline__ int uperm(int k) {
    return 16 * (2 * ((k >> 2) & 1) + ((k >> 5) & 1)) + 4 * ((k >> 3) & 3) + (k & 3);
}

// ---- pack one MLP's weights/biases into per-lane fragment order ----
__global__ void prep_frags(const float* __restrict__ w1, const float* __restrict__ b1,
                           const float* __restrict__ w2, const float* __restrict__ b2,
                           const float* __restrict__ w3, const float* __restrict__ b3,
                           const float* __restrict__ w4,
                           unsigned char* __restrict__ dstL,
                           unsigned char* __restrict__ dstR)
{
    int idx = blockIdx.x * blockDim.x + threadIdx.x;
    if (idx < 8192) {                      // w1f: [16 frags][64 lanes][8 f16]
        int L = (idx >> 3) & 63, j = idx & 7, f = idx >> 9;
        int q = L >> 4, mm = L & 15, t = f >> 2, s = f & 3;
        int k = 32 * s + 8 * q + j;
        ((_Float16*)(dstL + W1F))[idx] = (_Float16)w1[k * 64 + 16 * t + mm];
        return;
    }
    idx -= 8192;
    if (idx < 4096) {                      // w2f: [8][64][8]
        int L = (idx >> 3) & 63, j = idx & 7, f = idx >> 9;
        int q = L >> 4, mm = L & 15, t = f >> 1, s = f & 1;
        int u = uperm(32 * s + 8 * q + j);
        ((_Float16*)(dstL + W2F))[idx] = (_Float16)w2[u * 64 + 16 * t + mm];
        return;
    }
    idx -= 4096;
    if (idx < 2048) {                      // w3f: [4][64][8]
        int L = (idx >> 3) & 63, j = idx & 7, f = idx >> 9;
        int q = L >> 4, mm = L & 15, t = f >> 1, s = f & 1;
        int u = uperm(32 * s + 8 * q + j);
        ((_Float16*)(dstL + W3F))[idx] = (_Float16)w3[u * 32 + 16 * t + mm];
        return;
    }
    idx -= 2048;
    if (idx < 512) {                       // w4f
        int L = idx >> 3, j = idx & 7;
        int q = L >> 4, t = j >> 2, r = j & 3;
        ((float*)(dstR + 0))[idx] = w4[16 * t + 4 * q + r];
        return;
    }
    idx -= 512;
    if (idx < 1024) {                      // b1f
        int t = idx >> 8, L = (idx >> 2) & 63, r = idx & 3, q = L >> 4;
        ((float*)(dstR + 2048))[idx] = b1[16 * t + 4 * q + r];
        return;
    }
    idx -= 1024;
    if (idx < 1024) {                      // b2f
        int t = idx >> 8, L = (idx >> 2) & 63, r = idx & 3, q = L >> 4;
        ((float*)(dstR + 6144))[idx] = b2[16 * t + 4 * q + r];
        return;
    }
    idx -= 1024;
    if (idx < 512) {                       // b3f
        int t = idx >> 8, L = (idx >> 2) & 63, r = idx & 3, q = L >> 4;
        ((float*)(dstR + 10240))[idx] = b3[16 * t + 4 * q + r];
        return;
    }
}

// ---- convert node tables fp32 -> f16 ----
__global__ void prep_nodes(const float* __restrict__ xs, const float* __restrict__ xd,
                           _Float16* __restrict__ os, _Float16* __restrict__ od, int n4)
{
    int stride = gridDim.x * blockDim.x;
    for (int i = blockIdx.x * blockDim.x + threadIdx.x; i < n4; i += stride) {
        float4v a = ((const float4v*)xs)[i];
        float4v b = ((const float4v*)xd)[i];
        half4v ha, hb;
#pragma unroll
        for (int j = 0; j < 4; ++j) { ha[j] = (_Float16)a[j]; hb[j] = (_Float16)b[j]; }
        ((half4v*)os)[i] = ha;
        ((half4v*)od)[i] = hb;
    }
}

__device__ __forceinline__ half8 repack2(float4v lo, float4v hi) {
    half8 r;
#pragma unroll
    for (int j = 0; j < 4; ++j) r[j] = (_Float16)lrelu(lo[j]);
#pragma unroll
    for (int j = 0; j < 4; ++j) r[4 + j] = (_Float16)lrelu(hi[j]);
    return r;
}

// R2-style consume gather: lane (q,n) loads chunk q of edge n's 4 lines.
// These requests HIT L1/L2 (warmed 3 iterations earlier) -> no fills.
__device__ __forceinline__ void gather_tile(const _Float16* __restrict__ xs,
                                            const _Float16* __restrict__ xd,
                                            const int* __restrict__ eidx,
                                            int nE, int tile, int q, int n, int4* G)
{
    int e = tile * 16 + n;
    int ec = e < nE ? e : nE - 1;
    int si = eidx[ec];
    int di = eidx[nE + ec];
    const char* rs = (const char*)(xs + (size_t)si * 64);
    const char* rd = (const char*)(xd + (size_t)di * 64);
    G[0] = *(const int4*)(rs + 16 * q);
    G[1] = *(const int4*)(rs + 64 + 16 * q);
    G[2] = *(const int4*)(rd + 16 * q);
    G[3] = *(const int4*)(rd + 64 + 16 * q);
}

// warm pass: lane (c=q, n) touches line (edge n, combo c) once -> 64 distinct
// lines per instruction, exactly one 64B fill each.
__device__ __forceinline__ int4 warm_tile(const _Float16* __restrict__ xs,
                                          const _Float16* __restrict__ xd,
                                          const int* __restrict__ eidx,
                                          int nE, int tile, int c, int n)
{
    int e = tile * 16 + n;
    int ec = e < nE ? e : nE - 1;
    int idx = (c & 2) ? eidx[nE + ec] : eidx[ec];
    const char* base = (const char*)(((c & 2) ? xd : xs) + (size_t)idx * 64);
    return *(const int4*)(base + (c & 1) * 64);
}

__global__ __launch_bounds__(256, 2)
void edge_mlp_mfma(const unsigned char* __restrict__ ws,
                   const _Float16* __restrict__ xs, const _Float16* __restrict__ xd,
                   const int* __restrict__ eidx,
                   const float* __restrict__ eb4p, const float* __restrict__ wb4p,
                   float* __restrict__ out, int nE, int ntiles)
{
    __shared__ unsigned char lds[LDS_TOTAL];
    const int halfgrid = gridDim.x >> 1;
    const int m = blockIdx.x >= halfgrid ? 1 : 0;   // 0: exists-MLP, 1: weight-MLP
    const int bid = blockIdx.x - m * halfgrid;
    {
        const uint4* s = (const uint4*)(ws + m * LDS_W);
        uint4* d = (uint4*)lds;
        for (int i = threadIdx.x; i < LDS_W / 16; i += 256) d[i] = s[i];
        const uint4* s2 = (const uint4*)(ws + WS_REST_OFF + m * LDS_REST);
        uint4* d2 = (uint4*)(lds + LDS_W);
        for (int i = threadIdx.x; i < LDS_REST / 16; i += 256) d2[i] = s2[i];
    }
    __syncthreads();

    const int lane = threadIdx.x & 63;
    const int q = lane >> 4, n = lane & 15;
    const int wid = (bid << 2) | (threadIdx.x >> 6);
    const int nwaves = halfgrid << 2;
    const float b4s = m ? wb4p[0] : eb4p[0];
    float* __restrict__ outm = out + (m ? nE : 0);

    int4 Gcur[4], Gnxt[4];
    int4 W0 = {0,0,0,0}, W1 = {0,0,0,0}, W2 = {0,0,0,0}, junk = {0,0,0,0};

    int tile = wid;
    if (tile < ntiles) {
        int t1 = tile + nwaves;     if (t1 >= ntiles) t1 = ntiles - 1;
        int t2 = tile + 2 * nwaves; if (t2 >= ntiles) t2 = ntiles - 1;
        W0 = warm_tile(xs, xd, eidx, nE, tile, q, n);
        W1 = warm_tile(xs, xd, eidx, nE, t1, q, n);
        W2 = warm_tile(xs, xd, eidx, nE, t2, q, n);
        gather_tile(xs, xd, eidx, nE, tile, q, n, Gcur);
    }

#pragma unroll 1
    for (; tile < ntiles; tile += nwaves) {
        half8 B1[4];
#pragma unroll
        for (int s = 0; s < 4; ++s) B1[s] = __builtin_bit_cast(half8, Gcur[s]);

        // prefetch next tile's consume gather (hits warmed lines)
        int tn = tile + nwaves;
        if (tn < ntiles)
            gather_tile(xs, xd, eidx, nE, tn, q, n, Gnxt);

        // fold oldest warm (2 iters old -> complete), rotate, issue new warm
        junk.x ^= W0.x; junk.y ^= W0.y; junk.z ^= W0.z; junk.w ^= W0.w;
        W0 = W1; W1 = W2;
        {
            int tw = tile + 3 * nwaves;
            if (tw >= ntiles) tw = ntiles - 1;
            W2 = warm_tile(xs, xd, eidx, nE, tw, q, n);
        }

        // ---- layer 1: 128 -> 64 (bias via C-init from LDS) ----
        float4v acc[4];
#pragma unroll
        for (int t = 0; t < 4; ++t) {
            acc[t] = *(const float4v*)(lds + RB1F + (t * 64 + lane) * 16);
#pragma unroll
            for (int s = 0; s < 4; ++s) {
                half8 A = *(const half8*)(lds + W1F + ((t * 4 + s) * 64 + lane) * 16);
                acc[t] = __builtin_amdgcn_mfma_f32_16x16x32_f16(A, B1[s], acc[t], 0, 0, 0);
            }
        }

        // ---- layer 2: 64 -> 64 ----
        half8 B2[2] = { repack2(acc[0], acc[2]), repack2(acc[1], acc[3]) };
        float4v acc2[4];
#pragma unroll
        for (int t = 0; t < 4; ++t) {
            acc2[t] = *(const float4v*)(lds + RB2F + (t * 64 + lane) * 16);
#pragma unroll
            for (int s = 0; s < 2; ++s) {
                half8 A = *(const half8*)(lds + W2F + ((t * 2 + s) * 64 + lane) * 16);
                acc2[t] = __builtin_amdgcn_mfma_f32_16x16x32_f16(A, B2[s], acc2[t], 0, 0, 0);
            }
        }
        // ---- layer 3: 64 -> 32 ----
        half8 B3[2] = { repack2(acc2[0], acc2[2]), repack2(acc2[1], acc2[3]) };
        float4v acc3[2];
#pragma unroll
        for (int t = 0; t < 2; ++t) {
            acc3[t] = *(const float4v*)(lds + RB3F + (t * 64 + lane) * 16);
#pragma unroll
            for (int s = 0; s < 2; ++s) {
                half8 A = *(const half8*)(lds + W3F + ((t * 2 + s) * 64 + lane) * 16);
                acc3[t] = __builtin_amdgcn_mfma_f32_16x16x32_f16(A, B3[s], acc3[t], 0, 0, 0);
            }
        }
        // ---- layer 4: 32 -> 1 ----
        float4v w40 = *(const float4v*)(lds + RW4F + lane * 32);
        float4v w41 = *(const float4v*)(lds + RW4F + lane * 32 + 16);
        float o = 0.f;
#pragma unroll
        for (int r = 0; r < 4; ++r) o = fmaf(lrelu(acc3[0][r]), w40[r], o);
#pragma unroll
        for (int r = 0; r < 4; ++r) o = fmaf(lrelu(acc3[1][r]), w41[r], o);
        o += __shfl_xor(o, 16, 64);
        o += __shfl_xor(o, 32, 64);

        int e = tile * 16 + n;
        if (q == 0 && e < nE)
            outm[e] = o + b4s;

#pragma unroll
        for (int s = 0; s < 4; ++s) Gcur[s] = Gnxt[s];
    }

    // consume warm registers (never-taken, data-dependent guard defeats DCE)
    junk.x ^= W0.x ^ W1.x ^ W2.x;
    junk.y ^= W0.y ^ W1.y ^ W2.y;
    junk.z ^= W0.z ^ W1.z ^ W2.z;
    junk.w ^= W0.w ^ W1.w ^ W2.w;
    if (nE < 0 && (junk.x | junk.y | junk.z | junk.w) != 0)
        out[0] = -1.0f;
}

extern "C" void kernel_launch(void* const* d_in, const int* in_sizes, int n_in,
                              void* d_out, int out_size, void* d_ws, size_t ws_size,
                              hipStream_t stream)
{
    const float* x_src = (const float*)d_in[0];
    const float* x_dst = (const float*)d_in[1];
    const int*   eidx  = (const int*)d_in[2];
    const float* ew1 = (const float*)d_in[3];
    const float* eb1 = (const float*)d_in[4];
    const float* ww1 = (const float*)d_in[5];
    const float* wb1 = (const float*)d_in[6];
    const float* ew2 = (const float*)d_in[7];
    const float* eb2 = (const float*)d_in[8];
    const float* ww2 = (const float*)d_in[9];
    const float* wb2 = (const float*)d_in[10];
    const float* ew3 = (const float*)d_in[11];
    const float* eb3 = (const float*)d_in[12];
    const float* ww3 = (const float*)d_in[13];
    const float* wb3 = (const float*)d_in[14];
    const float* ew4 = (const float*)d_in[15];
    const float* eb4 = (const float*)d_in[16];
    const float* ww4 = (const float*)d_in[17];
    const float* wb4 = (const float*)d_in[18];
    float* out = (float*)d_out;

    const int nE = in_sizes[2] / 2;          // 2 x E index array (int32)
    const int nNodeElems = in_sizes[0];      // N_NODES * 64
    unsigned char* ws = (unsigned char*)d_ws;
    _Float16* xs16 = (_Float16*)(ws + WS_X16_OFF);
    _Float16* xd16 = xs16 + nNodeElems;

    prep_frags<<<68, 256, 0, stream>>>(ew1, eb1, ew2, eb2, ew3, eb3, ew4,
                                       ws, ws + WS_REST_OFF);
    prep_frags<<<68, 256, 0, stream>>>(ww1, wb1, ww2, wb2, ww3, wb3, ww4,
                                       ws + LDS_W, ws + WS_REST_OFF + LDS_REST);
    prep_nodes<<<1024, 256, 0, stream>>>(x_src, x_dst, xs16, xd16, nNodeElems / 4);

    const int ntiles = (nE + 15) / 16;
    edge_mlp_mfma<<<1024, 256, 0, stream>>>(ws, xs16, xd16, eidx, eb4, wb4,
                                            out, nE, ntiles);
}

// Round 4
// 345.333 us; speedup vs baseline: 3.8189x; 1.1240x over previous
//
#include <hip/hip_runtime.h>

// RegressorHybrid: per-edge 2x MLP (128->64->64->32->1, lrelu 0.01), E=2M, H=64.
// Round 10: registered weights. R9 (split-MLP, 2x occupancy) ran the SAME
// 290us as R6 -> shared-resource ceiling, not latency. The invariant pipe:
// 40 ds_read_b128 per tile-instance (L1 4b+16A, L2 4b+8A, L3 2b+4A, L4 2)
// x ~977 tile-inst/CU x ~12cyc = 469K cyc = 67% of the 696K-cyc runtime.
// LDS-issue-bandwidth-bound; occupancy adds proportional LDS traffic -> no
// gain. Fix: weights are loop-invariant -> w2f/w3f/w4/biases live in 96
// persistent VGPRs (loaded once from ws); only w1f (16KB) stays in LDS.
// Per-tile LDS 40->16 b128; L2-4 MFMAs take register A-operands (no lgkmcnt
// in their chain). Demand ~216 < 256 budget of launch_bounds(256,2): R7/R8's
// spill-chase needs demand>budget, R9 proved demand<budget allocates honest.
// Pairing fix: m=(blockIdx>>3)&1 pairs same-tile blocks at stride 8 -> same
// XCD (%8 preserved) AND temporally adjacent -> paired consume dedups in L2
// (R9's b/b+512 pairs drifted: FETCH doubled to 385MB).
// Warm-pass law (R1-R5) retained: one warm b128 per tile covers its 64 lines
// (1 fill each), 3 iterations ahead; consume gathers hit L1/L2.
// MFMA layouts: A[m=lane&15][k=(lane>>4)*8+j], B[k=(lane>>4)*8+j][n=lane&15],
//               C/D[row=4*(lane>>4)+reg][col=lane&15].

typedef _Float16 half8  __attribute__((ext_vector_type(8)));
typedef _Float16 half4v __attribute__((ext_vector_type(4)));
typedef float    float4v __attribute__((ext_vector_type(4)));

#define MLP_W_BYTES 28672          // w1f 16384 + w2f 8192 + w3f 4096
#define MLP_R_BYTES 12288          // w4f 2048 + b1f 4096 + b2f 4096 + b3f 2048
#define W1F 0
#define W2F 16384
#define W3F 24576
#define LDS_TOTAL   16384          // w1f only
#define WS_REST_OFF 57344
#define WS_X16_OFF  81920

__device__ __forceinline__ float lrelu(float x) { return fmaxf(x, 0.01f * x); }

__device__ __forceinline__ int uperm(int k) {
    return 16 * (2 * ((k >> 2) & 1) + ((k >> 5) & 1)) + 4 * ((k >> 3) & 3) + (k & 3);
}

// ---- pack one MLP's weights/biases into per-lane fragment order ----
__global__ void prep_frags(const float* __restrict__ w1, const float* __restrict__ b1,
                           const float* __restrict__ w2, const float* __restrict__ b2,
                           const float* __restrict__ w3, const float* __restrict__ b3,
                           const float* __restrict__ w4,
                           unsigned char* __restrict__ dstL,
                           unsigned char* __restrict__ dstR)
{
    int idx = blockIdx.x * blockDim.x + threadIdx.x;
    if (idx < 8192) {                      // w1f: [16 frags][64 lanes][8 f16]
        int L = (idx >> 3) & 63, j = idx & 7, f = idx >> 9;
        int q = L >> 4, mm = L & 15, t = f >> 2, s = f & 3;
        int k = 32 * s + 8 * q + j;
        ((_Float16*)(dstL + W1F))[idx] = (_Float16)w1[k * 64 + 16 * t + mm];
        return;
    }
    idx -= 8192;
    if (idx < 4096) {                      // w2f: [8][64][8]
        int L = (idx >> 3) & 63, j = idx & 7, f = idx >> 9;
        int q = L >> 4, mm = L & 15, t = f >> 1, s = f & 1;
        int u = uperm(32 * s + 8 * q + j);
        ((_Float16*)(dstL + W2F))[idx] = (_Float16)w2[u * 64 + 16 * t + mm];
        return;
    }
    idx -= 4096;
    if (idx < 2048) {                      // w3f: [4][64][8]
        int L = (idx >> 3) & 63, j = idx & 7, f = idx >> 9;
        int q = L >> 4, mm = L & 15, t = f >> 1, s = f & 1;
        int u = uperm(32 * s + 8 * q + j);
        ((_Float16*)(dstL + W3F))[idx] = (_Float16)w3[u * 32 + 16 * t + mm];
        return;
    }
    idx -= 2048;
    if (idx < 512) {                       // w4f
        int L = idx >> 3, j = idx & 7;
        int q = L >> 4, t = j >> 2, r = j & 3;
        ((float*)(dstR + 0))[idx] = w4[16 * t + 4 * q + r];
        return;
    }
    idx -= 512;
    if (idx < 1024) {                      // b1f
        int t = idx >> 8, L = (idx >> 2) & 63, r = idx & 3, q = L >> 4;
        ((float*)(dstR + 2048))[idx] = b1[16 * t + 4 * q + r];
        return;
    }
    idx -= 1024;
    if (idx < 1024) {                      // b2f
        int t = idx >> 8, L = (idx >> 2) & 63, r = idx & 3, q = L >> 4;
        ((float*)(dstR + 6144))[idx] = b2[16 * t + 4 * q + r];
        return;
    }
    idx -= 1024;
    if (idx < 512) {                       // b3f
        int t = idx >> 8, L = (idx >> 2) & 63, r = idx & 3, q = L >> 4;
        ((float*)(dstR + 10240))[idx] = b3[16 * t + 4 * q + r];
        return;
    }
}

// ---- convert node tables fp32 -> f16 ----
__global__ void prep_nodes(const float* __restrict__ xs, const float* __restrict__ xd,
                           _Float16* __restrict__ os, _Float16* __restrict__ od, int n4)
{
    int stride = gridDim.x * blockDim.x;
    for (int i = blockIdx.x * blockDim.x + threadIdx.x; i < n4; i += stride) {
        float4v a = ((const float4v*)xs)[i];
        float4v b = ((const float4v*)xd)[i];
        half4v ha, hb;
#pragma unroll
        for (int j = 0; j < 4; ++j) { ha[j] = (_Float16)a[j]; hb[j] = (_Float16)b[j]; }
        ((half4v*)os)[i] = ha;
        ((half4v*)od)[i] = hb;
    }
}

__device__ __forceinline__ half8 repack2(float4v lo, float4v hi) {
    half8 r;
#pragma unroll
    for (int j = 0; j < 4; ++j) r[j] = (_Float16)lrelu(lo[j]);
#pragma unroll
    for (int j = 0; j < 4; ++j) r[4 + j] = (_Float16)lrelu(hi[j]);
    return r;
}

// R2-style consume gather: lane (q,n) loads chunk q of edge n's 4 lines.
// These requests HIT L1/L2 (warmed 3 iterations earlier) -> no fills.
__device__ __forceinline__ void gather_tile(const _Float16* __restrict__ xs,
                                            const _Float16* __restrict__ xd,
                                            const int* __restrict__ eidx,
                                            int nE, int tile, int q, int n, int4* G)
{
    int e = tile * 16 + n;
    int ec = e < nE ? e : nE - 1;
    int si = eidx[ec];
    int di = eidx[nE + ec];
    const char* rs = (const char*)(xs + (size_t)si * 64);
    const char* rd = (const char*)(xd + (size_t)di * 64);
    G[0] = *(const int4*)(rs + 16 * q);
    G[1] = *(const int4*)(rs + 64 + 16 * q);
    G[2] = *(const int4*)(rd + 16 * q);
    G[3] = *(const int4*)(rd + 64 + 16 * q);
}

// warm pass: lane (c=q, n) touches line (edge n, combo c) once -> 64 distinct
// lines per instruction, exactly one 64B fill each.
__device__ __forceinline__ int4 warm_tile(const _Float16* __restrict__ xs,
                                          const _Float16* __restrict__ xd,
                                          const int* __restrict__ eidx,
                                          int nE, int tile, int c, int n)
{
    int e = tile * 16 + n;
    int ec = e < nE ? e : nE - 1;
    int idx = (c & 2) ? eidx[nE + ec] : eidx[ec];
    const char* base = (const char*)(((c & 2) ? xd : xs) + (size_t)idx * 64);
    return *(const int4*)(base + (c & 1) * 64);
}

__global__ __launch_bounds__(256, 2)
void edge_mlp_mfma(const unsigned char* __restrict__ ws,
                   const _Float16* __restrict__ xs, const _Float16* __restrict__ xd,
                   const int* __restrict__ eidx,
                   const float* __restrict__ eb4p, const float* __restrict__ wb4p,
                   float* __restrict__ out, int nE, int ntiles)
{
    __shared__ unsigned char lds[LDS_TOTAL];
    // stride-8 pairing: blocks 16k+j and 16k+8+j (j<8) run the same tiles for
    // m=0/1 -> same XCD (%8 preserved) and adjacent dispatch -> L2 dedup.
    const int m = (blockIdx.x >> 3) & 1;
    const int bid = (blockIdx.x & 7) | ((blockIdx.x >> 4) << 3);
    const unsigned char* wbase = ws + m * MLP_W_BYTES;
    const unsigned char* rbase = ws + WS_REST_OFF + m * MLP_R_BYTES;
    {
        const uint4* s = (const uint4*)(wbase + W1F);
        uint4* d = (uint4*)lds;
        for (int i = threadIdx.x; i < LDS_TOTAL / 16; i += 256) d[i] = s[i];
    }

    const int lane = threadIdx.x & 63;
    const int q = lane >> 4, n = lane & 15;
    const int wid = (bid << 2) | (threadIdx.x >> 6);
    const int nwaves = gridDim.x << 1;     // (grid/2 blocks per MLP) * 4 waves
    const float b4s = m ? wb4p[0] : eb4p[0];
    float* __restrict__ outm = out + (m ? nE : 0);

    // ---- persistent register weights: w2f, w3f, w4, b1f, b2f, b3f ----
    half8 w2f[8], w3f[4];
#pragma unroll
    for (int f = 0; f < 8; ++f)
        w2f[f] = *(const half8*)(wbase + W2F + (f * 64 + lane) * 16);
#pragma unroll
    for (int f = 0; f < 4; ++f)
        w3f[f] = *(const half8*)(wbase + W3F + (f * 64 + lane) * 16);
    float4v w40 = *(const float4v*)(rbase + 0 + lane * 32);
    float4v w41 = *(const float4v*)(rbase + 0 + lane * 32 + 16);
    float4v b1f[4], b2f[4], b3f[2];
#pragma unroll
    for (int t = 0; t < 4; ++t)
        b1f[t] = *(const float4v*)(rbase + 2048 + (t * 64 + lane) * 16);
#pragma unroll
    for (int t = 0; t < 4; ++t)
        b2f[t] = *(const float4v*)(rbase + 6144 + (t * 64 + lane) * 16);
#pragma unroll
    for (int t = 0; t < 2; ++t)
        b3f[t] = *(const float4v*)(rbase + 10240 + (t * 64 + lane) * 16);

    __syncthreads();

    int4 Gcur[4], Gnxt[4];
    int4 W0 = {0,0,0,0}, W1 = {0,0,0,0}, W2 = {0,0,0,0}, junk = {0,0,0,0};

    int tile = wid;
    if (tile < ntiles) {
        int t1 = tile + nwaves;     if (t1 >= ntiles) t1 = ntiles - 1;
        int t2 = tile + 2 * nwaves; if (t2 >= ntiles) t2 = ntiles - 1;
        W0 = warm_tile(xs, xd, eidx, nE, tile, q, n);
        W1 = warm_tile(xs, xd, eidx, nE, t1, q, n);
        W2 = warm_tile(xs, xd, eidx, nE, t2, q, n);
        gather_tile(xs, xd, eidx, nE, tile, q, n, Gcur);
    }

#pragma unroll 1
    for (; tile < ntiles; tile += nwaves) {
        half8 B1[4];
#pragma unroll
        for (int s = 0; s < 4; ++s) B1[s] = __builtin_bit_cast(half8, Gcur[s]);

        // prefetch next tile's consume gather (hits warmed lines)
        int tn = tile + nwaves;
        if (tn < ntiles)
            gather_tile(xs, xd, eidx, nE, tn, q, n, Gnxt);

        // fold oldest warm (2 iters old -> complete), rotate, issue new warm
        junk.x ^= W0.x; junk.y ^= W0.y; junk.z ^= W0.z; junk.w ^= W0.w;
        W0 = W1; W1 = W2;
        {
            int tw = tile + 3 * nwaves;
            if (tw >= ntiles) tw = ntiles - 1;
            W2 = warm_tile(xs, xd, eidx, nE, tw, q, n);
        }

        // ---- layer 1: 128 -> 64 (bias C-init from regs, A from LDS) ----
        float4v acc[4];
#pragma unroll
        for (int t = 0; t < 4; ++t) {
            acc[t] = b1f[t];
#pragma unroll
            for (int s = 0; s < 4; ++s) {
                half8 A = *(const half8*)(lds + W1F + ((t * 4 + s) * 64 + lane) * 16);
                acc[t] = __builtin_amdgcn_mfma_f32_16x16x32_f16(A, B1[s], acc[t], 0, 0, 0);
            }
        }

        // ---- layer 2: 64 -> 64 (A from regs) ----
        half8 B2[2] = { repack2(acc[0], acc[2]), repack2(acc[1], acc[3]) };
        float4v acc2[4];
#pragma unroll
        for (int t = 0; t < 4; ++t) {
            acc2[t] = b2f[t];
#pragma unroll
            for (int s = 0; s < 2; ++s)
                acc2[t] = __builtin_amdgcn_mfma_f32_16x16x32_f16(w2f[t * 2 + s], B2[s], acc2[t], 0, 0, 0);
        }
        // ---- layer 3: 64 -> 32 (A from regs) ----
        half8 B3[2] = { repack2(acc2[0], acc2[2]), repack2(acc2[1], acc2[3]) };
        float4v acc3[2];
#pragma unroll
        for (int t = 0; t < 2; ++t) {
            acc3[t] = b3f[t];
#pragma unroll
            for (int s = 0; s < 2; ++s)
                acc3[t] = __builtin_amdgcn_mfma_f32_16x16x32_f16(w3f[t * 2 + s], B3[s], acc3[t], 0, 0, 0);
        }
        // ---- layer 4: 32 -> 1 (w4 in regs) ----
        float o = 0.f;
#pragma unroll
        for (int r = 0; r < 4; ++r) o = fmaf(lrelu(acc3[0][r]), w40[r], o);
#pragma unroll
        for (int r = 0; r < 4; ++r) o = fmaf(lrelu(acc3[1][r]), w41[r], o);
        o += __shfl_xor(o, 16, 64);
        o += __shfl_xor(o, 32, 64);

        int e = tile * 16 + n;
        if (q == 0 && e < nE)
            outm[e] = o + b4s;

#pragma unroll
        for (int s = 0; s < 4; ++s) Gcur[s] = Gnxt[s];
    }

    // consume warm registers (never-taken, data-dependent guard defeats DCE)
    junk.x ^= W0.x ^ W1.x ^ W2.x;
    junk.y ^= W0.y ^ W1.y ^ W2.y;
    junk.z ^= W0.z ^ W1.z ^ W2.z;
    junk.w ^= W0.w ^ W1.w ^ W2.w;
    if (nE < 0 && (junk.x | junk.y | junk.z | junk.w) != 0)
        out[0] = -1.0f;
}

extern "C" void kernel_launch(void* const* d_in, const int* in_sizes, int n_in,
                              void* d_out, int out_size, void* d_ws, size_t ws_size,
                              hipStream_t stream)
{
    const float* x_src = (const float*)d_in[0];
    const float* x_dst = (const float*)d_in[1];
    const int*   eidx  = (const int*)d_in[2];
    const float* ew1 = (const float*)d_in[3];
    const float* eb1 = (const float*)d_in[4];
    const float* ww1 = (const float*)d_in[5];
    const float* wb1 = (const float*)d_in[6];
    const float* ew2 = (const float*)d_in[7];
    const float* eb2 = (const float*)d_in[8];
    const float* ww2 = (const float*)d_in[9];
    const float* wb2 = (const float*)d_in[10];
    const float* ew3 = (const float*)d_in[11];
    const float* eb3 = (const float*)d_in[12];
    const float* ww3 = (const float*)d_in[13];
    const float* wb3 = (const float*)d_in[14];
    const float* ew4 = (const float*)d_in[15];
    const float* eb4 = (const float*)d_in[16];
    const float* ww4 = (const float*)d_in[17];
    const float* wb4 = (const float*)d_in[18];
    float* out = (float*)d_out;

    const int nE = in_sizes[2] / 2;          // 2 x E index array (int32)
    const int nNodeElems = in_sizes[0];      // N_NODES * 64
    unsigned char* ws = (unsigned char*)d_ws;
    _Float16* xs16 = (_Float16*)(ws + WS_X16_OFF);
    _Float16* xd16 = xs16 + nNodeElems;

    prep_frags<<<68, 256, 0, stream>>>(ew1, eb1, ew2, eb2, ew3, eb3, ew4,
                                       ws, ws + WS_REST_OFF);
    prep_frags<<<68, 256, 0, stream>>>(ww1, wb1, ww2, wb2, ww3, wb3, ww4,
                                       ws + MLP_W_BYTES, ws + WS_REST_OFF + MLP_R_BYTES);
    prep_nodes<<<1024, 256, 0, stream>>>(x_src, x_dst, xs16, xd16, nNodeElems / 4);

    const int ntiles = (nE + 15) / 16;
    edge_mlp_mfma<<<1024, 256, 0, stream>>>(ws, xs16, xd16, eidx, eb4, wb4,
                                            out, nE, ntiles);
}

// Round 6
// 295.143 us; speedup vs baseline: 4.4683x; 1.1701x over previous
//
#include <hip/hip_runtime.h>

// RegressorHybrid: per-edge 2x MLP (128->64->64->32->1, lrelu 0.01), E=2M, H=64.
// Round 12 = Round 11 with the cvt_pkrtz type fix (builtin returns __fp16x2;
// bit_cast to _Float16x2). R11 theory untested (compile error), restated:
// R10 (registered weights, 258us): VALU 38%, MFMA 19%, LDS-pipe ~20%, ~40%
// idle at 2 waves/SIMD (unified VGPR+AGPR ~216 -> weights live in AGPRs,
// VGPR_Count 120 counts arch only). Occupancy proven a non-lever (R9 4
// waves/SIMD == R10 2 waves) -> the idle is a per-iteration dependent chain:
// gather_tile(t+1) did eidx load (L2/HBM 200-900cy) -> addr -> G loads (L1
// 120cy) issued only 1 iter ahead. Fix 1: rotating int2 I1/I2/I3 prefetches
// eidx 3 tiles ahead; gather issues at loop top from registers (pure L1 hit,
// covered); warm(t+3) reuses the same prefetched pair (-2 eidx loads/iter).
// Fix 2: repack via v_cvt_pkrtz_f16_f32 + v_pk_mul/max_f16: 12 VALU per 8
// values vs 24 (lrelu in f16 after RTZ cvt; absmax drift expected <2e-4).
// Kept from R10: w2f/w3f/w4/biases in ~96 persistent AGPRs, w1f (16KB) in
// LDS (16 ds_read_b128/tile), stride-8 block pairing (m=(bid>>3)&1) for L2
// warm dedup (FETCH 185MB = raw), launch_bounds(256,2) (honest alloc, no
// spill-chase), warm law R1-R5: one warm b128 covers the tile's 64 lines.
// MFMA layouts: A[m=lane&15][k=(lane>>4)*8+j], B[k=(lane>>4)*8+j][n=lane&15],
//               C/D[row=4*(lane>>4)+reg][col=lane&15].

typedef _Float16 half8  __attribute__((ext_vector_type(8)));
typedef _Float16 half4v __attribute__((ext_vector_type(4)));
typedef _Float16 half2v __attribute__((ext_vector_type(2)));
typedef float    float4v __attribute__((ext_vector_type(4)));

#define MLP_W_BYTES 28672          // w1f 16384 + w2f 8192 + w3f 4096
#define MLP_R_BYTES 12288          // w4f 2048 + b1f 4096 + b2f 4096 + b3f 2048
#define W1F 0
#define W2F 16384
#define W3F 24576
#define LDS_TOTAL   16384          // w1f only
#define WS_REST_OFF 57344
#define WS_X16_OFF  81920

__device__ __forceinline__ float lrelu(float x) { return fmaxf(x, 0.01f * x); }

__device__ __forceinline__ int uperm(int k) {
    return 16 * (2 * ((k >> 2) & 1) + ((k >> 5) & 1)) + 4 * ((k >> 3) & 3) + (k & 3);
}

// ---- pack one MLP's weights/biases into per-lane fragment order ----
__global__ void prep_frags(const float* __restrict__ w1, const float* __restrict__ b1,
                           const float* __restrict__ w2, const float* __restrict__ b2,
                           const float* __restrict__ w3, const float* __restrict__ b3,
                           const float* __restrict__ w4,
                           unsigned char* __restrict__ dstL,
                           unsigned char* __restrict__ dstR)
{
    int idx = blockIdx.x * blockDim.x + threadIdx.x;
    if (idx < 8192) {                      // w1f: [16 frags][64 lanes][8 f16]
        int L = (idx >> 3) & 63, j = idx & 7, f = idx >> 9;
        int q = L >> 4, mm = L & 15, t = f >> 2, s = f & 3;
        int k = 32 * s + 8 * q + j;
        ((_Float16*)(dstL + W1F))[idx] = (_Float16)w1[k * 64 + 16 * t + mm];
        return;
    }
    idx -= 8192;
    if (idx < 4096) {                      // w2f: [8][64][8]
        int L = (idx >> 3) & 63, j = idx & 7, f = idx >> 9;
        int q = L >> 4, mm = L & 15, t = f >> 1, s = f & 1;
        int u = uperm(32 * s + 8 * q + j);
        ((_Float16*)(dstL + W2F))[idx] = (_Float16)w2[u * 64 + 16 * t + mm];
        return;
    }
    idx -= 4096;
    if (idx < 2048) {                      // w3f: [4][64][8]
        int L = (idx >> 3) & 63, j = idx & 7, f = idx >> 9;
        int q = L >> 4, mm = L & 15, t = f >> 1, s = f & 1;
        int u = uperm(32 * s + 8 * q + j);
        ((_Float16*)(dstL + W3F))[idx] = (_Float16)w3[u * 32 + 16 * t + mm];
        return;
    }
    idx -= 2048;
    if (idx < 512) {                       // w4f
        int L = idx >> 3, j = idx & 7;
        int q = L >> 4, t = j >> 2, r = j & 3;
        ((float*)(dstR + 0))[idx] = w4[16 * t + 4 * q + r];
        return;
    }
    idx -= 512;
    if (idx < 1024) {                      // b1f
        int t = idx >> 8, L = (idx >> 2) & 63, r = idx & 3, q = L >> 4;
        ((float*)(dstR + 2048))[idx] = b1[16 * t + 4 * q + r];
        return;
    }
    idx -= 1024;
    if (idx < 1024) {                      // b2f
        int t = idx >> 8, L = (idx >> 2) & 63, r = idx & 3, q = L >> 4;
        ((float*)(dstR + 6144))[idx] = b2[16 * t + 4 * q + r];
        return;
    }
    idx -= 1024;
    if (idx < 512) {                       // b3f
        int t = idx >> 8, L = (idx >> 2) & 63, r = idx & 3, q = L >> 4;
        ((float*)(dstR + 10240))[idx] = b3[16 * t + 4 * q + r];
        return;
    }
}

// ---- convert node tables fp32 -> f16 ----
__global__ void prep_nodes(const float* __restrict__ xs, const float* __restrict__ xd,
                           _Float16* __restrict__ os, _Float16* __restrict__ od, int n4)
{
    int stride = gridDim.x * blockDim.x;
    for (int i = blockIdx.x * blockDim.x + threadIdx.x; i < n4; i += stride) {
        float4v a = ((const float4v*)xs)[i];
        float4v b = ((const float4v*)xd)[i];
        half4v ha, hb;
#pragma unroll
        for (int j = 0; j < 4; ++j) { ha[j] = (_Float16)a[j]; hb[j] = (_Float16)b[j]; }
        ((half4v*)os)[i] = ha;
        ((half4v*)od)[i] = hb;
    }
}

// packed repack: cvt_pkrtz (2 f32 -> 2 f16, 1 inst) then lrelu in f16 via
// v_pk_mul_f16 + v_pk_max_f16: 12 VALU per 8 values (was 24).
// builtin returns __fp16x2 -> bit_cast to _Float16x2 (same IEEE binary16).
__device__ __forceinline__ half2v cvt_pk(float a, float b) {
    return __builtin_bit_cast(half2v, __builtin_amdgcn_cvt_pkrtz(a, b));
}

__device__ __forceinline__ half8 repack2(float4v lo, float4v hi) {
    half8 r;
#pragma unroll
    for (int j = 0; j < 2; ++j) {
        half2v a = cvt_pk(lo[2 * j], lo[2 * j + 1]);
        half2v sa = a * (_Float16)0.01f;
        half2v ma = __builtin_elementwise_max(a, sa);
        r[2 * j] = ma[0]; r[2 * j + 1] = ma[1];
        half2v b = cvt_pk(hi[2 * j], hi[2 * j + 1]);
        half2v sb = b * (_Float16)0.01f;
        half2v mb = __builtin_elementwise_max(b, sb);
        r[4 + 2 * j] = mb[0]; r[4 + 2 * j + 1] = mb[1];
    }
    return r;
}

// eidx prefetch: (src,dst) node index pair for this lane's edge of a tile
__device__ __forceinline__ int2 load_eidx(const int* __restrict__ eidx,
                                          int nE, int tile, int n)
{
    int e = tile * 16 + n;
    int ec = e < nE ? e : nE - 1;
    return make_int2(eidx[ec], eidx[nE + ec]);
}

// R2-style consume gather from prefetched indices: lane (q,n) loads chunk q
// of edge n's 4 lines. Requests HIT L1/L2 (warmed 3 iterations earlier).
__device__ __forceinline__ void gather_tile(const _Float16* __restrict__ xs,
                                            const _Float16* __restrict__ xd,
                                            int2 sd, int q, int4* G)
{
    const char* rs = (const char*)(xs + (size_t)sd.x * 64);
    const char* rd = (const char*)(xd + (size_t)sd.y * 64);
    G[0] = *(const int4*)(rs + 16 * q);
    G[1] = *(const int4*)(rs + 64 + 16 * q);
    G[2] = *(const int4*)(rd + 16 * q);
    G[3] = *(const int4*)(rd + 64 + 16 * q);
}

// warm pass from prefetched indices: lane (c=q, n) touches line (edge n,
// combo c) once -> 64 distinct lines per instruction, one 64B fill each.
__device__ __forceinline__ int4 warm_tile(const _Float16* __restrict__ xs,
                                          const _Float16* __restrict__ xd,
                                          int2 sd, int c)
{
    int idx = (c & 2) ? sd.y : sd.x;
    const char* base = (const char*)(((c & 2) ? xd : xs) + (size_t)idx * 64);
    return *(const int4*)(base + (c & 1) * 64);
}

__global__ __launch_bounds__(256, 2)
void edge_mlp_mfma(const unsigned char* __restrict__ ws,
                   const _Float16* __restrict__ xs, const _Float16* __restrict__ xd,
                   const int* __restrict__ eidx,
                   const float* __restrict__ eb4p, const float* __restrict__ wb4p,
                   float* __restrict__ out, int nE, int ntiles)
{
    __shared__ unsigned char lds[LDS_TOTAL];
    // stride-8 pairing: blocks 16k+j and 16k+8+j (j<8) run the same tiles for
    // m=0/1 -> same XCD (%8 preserved) and adjacent dispatch -> L2 dedup.
    const int m = (blockIdx.x >> 3) & 1;
    const int bid = (blockIdx.x & 7) | ((blockIdx.x >> 4) << 3);
    const unsigned char* wbase = ws + m * MLP_W_BYTES;
    const unsigned char* rbase = ws + WS_REST_OFF + m * MLP_R_BYTES;
    {
        const uint4* s = (const uint4*)(wbase + W1F);
        uint4* d = (uint4*)lds;
        for (int i = threadIdx.x; i < LDS_TOTAL / 16; i += 256) d[i] = s[i];
    }

    const int lane = threadIdx.x & 63;
    const int q = lane >> 4, n = lane & 15;
    const int wid = (bid << 2) | (threadIdx.x >> 6);
    const int nwaves = gridDim.x << 1;     // (grid/2 blocks per MLP) * 4 waves
    const float b4s = m ? wb4p[0] : eb4p[0];
    float* __restrict__ outm = out + (m ? nE : 0);

    // ---- persistent register weights: w2f, w3f, w4, b1f, b2f, b3f ----
    half8 w2f[8], w3f[4];
#pragma unroll
    for (int f = 0; f < 8; ++f)
        w2f[f] = *(const half8*)(wbase + W2F + (f * 64 + lane) * 16);
#pragma unroll
    for (int f = 0; f < 4; ++f)
        w3f[f] = *(const half8*)(wbase + W3F + (f * 64 + lane) * 16);
    float4v w40 = *(const float4v*)(rbase + 0 + lane * 32);
    float4v w41 = *(const float4v*)(rbase + 0 + lane * 32 + 16);
    float4v b1f[4], b2f[4], b3f[2];
#pragma unroll
    for (int t = 0; t < 4; ++t)
        b1f[t] = *(const float4v*)(rbase + 2048 + (t * 64 + lane) * 16);
#pragma unroll
    for (int t = 0; t < 4; ++t)
        b2f[t] = *(const float4v*)(rbase + 6144 + (t * 64 + lane) * 16);
#pragma unroll
    for (int t = 0; t < 2; ++t)
        b3f[t] = *(const float4v*)(rbase + 10240 + (t * 64 + lane) * 16);

    __syncthreads();

    int4 Gcur[4], Gnxt[4];
    int4 W0 = {0,0,0,0}, W1 = {0,0,0,0}, W2 = {0,0,0,0}, junk = {0,0,0,0};
    int2 I1 = {0,0}, I2 = {0,0}, I3 = {0,0};

    int tile = wid;
    if (tile < ntiles) {
        int t1 = tile + nwaves;     if (t1 >= ntiles) t1 = ntiles - 1;
        int t2 = tile + 2 * nwaves; if (t2 >= ntiles) t2 = ntiles - 1;
        int t3 = tile + 3 * nwaves; if (t3 >= ntiles) t3 = ntiles - 1;
        int2 I0 = load_eidx(eidx, nE, tile, n);
        I1 = load_eidx(eidx, nE, t1, n);
        I2 = load_eidx(eidx, nE, t2, n);
        I3 = load_eidx(eidx, nE, t3, n);
        W0 = warm_tile(xs, xd, I0, q);
        W1 = warm_tile(xs, xd, I1, q);
        W2 = warm_tile(xs, xd, I2, q);
        gather_tile(xs, xd, I0, q, Gcur);
    }

#pragma unroll 1
    for (; tile < ntiles; tile += nwaves) {
        half8 B1[4];
#pragma unroll
        for (int s = 0; s < 4; ++s) B1[s] = __builtin_bit_cast(half8, Gcur[s]);

        // next tile's consume gather: address already in registers (I1),
        // requests hit warmed L1/L2 lines -> no dependent eidx chain.
        int tn = tile + nwaves;
        if (tn < ntiles)
            gather_tile(xs, xd, I1, q, Gnxt);

        // fold oldest warm (3 iters old -> complete), rotate, issue new warm
        // for tile+3nw from prefetched I3.
        junk.x ^= W0.x; junk.y ^= W0.y; junk.z ^= W0.z; junk.w ^= W0.w;
        W0 = W1; W1 = W2;
        W2 = warm_tile(xs, xd, I3, q);

        // rotate eidx pipeline; issue fetch for tile+4nw
        {
            int t4 = tile + 4 * nwaves; if (t4 >= ntiles) t4 = ntiles - 1;
            I1 = I2; I2 = I3;
            I3 = load_eidx(eidx, nE, t4, n);
        }

        // ---- layer 1: 128 -> 64 (bias C-init from regs, A from LDS) ----
        float4v acc[4];
#pragma unroll
        for (int t = 0; t < 4; ++t) {
            acc[t] = b1f[t];
#pragma unroll
            for (int s = 0; s < 4; ++s) {
                half8 A = *(const half8*)(lds + W1F + ((t * 4 + s) * 64 + lane) * 16);
                acc[t] = __builtin_amdgcn_mfma_f32_16x16x32_f16(A, B1[s], acc[t], 0, 0, 0);
            }
        }

        // ---- layer 2: 64 -> 64 (A from regs) ----
        half8 B2[2] = { repack2(acc[0], acc[2]), repack2(acc[1], acc[3]) };
        float4v acc2[4];
#pragma unroll
        for (int t = 0; t < 4; ++t) {
            acc2[t] = b2f[t];
#pragma unroll
            for (int s = 0; s < 2; ++s)
                acc2[t] = __builtin_amdgcn_mfma_f32_16x16x32_f16(w2f[t * 2 + s], B2[s], acc2[t], 0, 0, 0);
        }
        // ---- layer 3: 64 -> 32 (A from regs) ----
        half8 B3[2] = { repack2(acc2[0], acc2[2]), repack2(acc2[1], acc2[3]) };
        float4v acc3[2];
#pragma unroll
        for (int t = 0; t < 2; ++t) {
            acc3[t] = b3f[t];
#pragma unroll
            for (int s = 0; s < 2; ++s)
                acc3[t] = __builtin_amdgcn_mfma_f32_16x16x32_f16(w3f[t * 2 + s], B3[s], acc3[t], 0, 0, 0);
        }
        // ---- layer 4: 32 -> 1 (w4 in regs) ----
        float o = 0.f;
#pragma unroll
        for (int r = 0; r < 4; ++r) o = fmaf(lrelu(acc3[0][r]), w40[r], o);
#pragma unroll
        for (int r = 0; r < 4; ++r) o = fmaf(lrelu(acc3[1][r]), w41[r], o);
        o += __shfl_xor(o, 16, 64);
        o += __shfl_xor(o, 32, 64);

        int e = tile * 16 + n;
        if (q == 0 && e < nE)
            outm[e] = o + b4s;

#pragma unroll
        for (int s = 0; s < 4; ++s) Gcur[s] = Gnxt[s];
    }

    // consume warm registers (never-taken, data-dependent guard defeats DCE)
    junk.x ^= W0.x ^ W1.x ^ W2.x;
    junk.y ^= W0.y ^ W1.y ^ W2.y;
    junk.z ^= W0.z ^ W1.z ^ W2.z;
    junk.w ^= W0.w ^ W1.w ^ W2.w;
    if (nE < 0 && (junk.x | junk.y | junk.z | junk.w) != 0)
        out[0] = -1.0f;
}

extern "C" void kernel_launch(void* const* d_in, const int* in_sizes, int n_in,
                              void* d_out, int out_size, void* d_ws, size_t ws_size,
                              hipStream_t stream)
{
    const float* x_src = (const float*)d_in[0];
    const float* x_dst = (const float*)d_in[1];
    const int*   eidx  = (const int*)d_in[2];
    const float* ew1 = (const float*)d_in[3];
    const float* eb1 = (const float*)d_in[4];
    const float* ww1 = (const float*)d_in[5];
    const float* wb1 = (const float*)d_in[6];
    const float* ew2 = (const float*)d_in[7];
    const float* eb2 = (const float*)d_in[8];
    const float* ww2 = (const float*)d_in[9];
    const float* wb2 = (const float*)d_in[10];
    const float* ww3 = (const float*)d_in[13];
    const float* ew3 = (const float*)d_in[11];
    const float* eb3 = (const float*)d_in[12];
    const float* wb3 = (const float*)d_in[14];
    const float* ew4 = (const float*)d_in[15];
    const float* eb4 = (const float*)d_in[16];
    const float* ww4 = (const float*)d_in[17];
    const float* wb4 = (const float*)d_in[18];
    float* out = (float*)d_out;

    const int nE = in_sizes[2] / 2;          // 2 x E index array (int32)
    const int nNodeElems = in_sizes[0];      // N_NODES * 64
    unsigned char* ws = (unsigned char*)d_ws;
    _Float16* xs16 = (_Float16*)(ws + WS_X16_OFF);
    _Float16* xd16 = xs16 + nNodeElems;

    prep_frags<<<68, 256, 0, stream>>>(ew1, eb1, ew2, eb2, ew3, eb3, ew4,
                                       ws, ws + WS_REST_OFF);
    prep_frags<<<68, 256, 0, stream>>>(ww1, wb1, ww2, wb2, ww3, wb3, ww4,
                                       ws + MLP_W_BYTES, ws + WS_REST_OFF + MLP_R_BYTES);
    prep_nodes<<<1024, 256, 0, stream>>>(x_src, x_dst, xs16, xd16, nNodeElems / 4);

    const int ntiles = (nE + 15) / 16;
    edge_mlp_mfma<<<1024, 256, 0, stream>>>(ws, xs16, xd16, eidx, eb4, wb4,
                                            out, nE, ntiles);
}